// Round 7
// baseline (5740.985 us; speedup 1.0000x reference)
//
#include <hip/hip_runtime.h>
#include <hip/hip_bf16.h>

// LSTM decoder: L=512, B=64, A=256, I=256, H=512, 4H=2048.
// R7: tag-in-data handshake. h published as self-validating u64 words
// ([tag16|bf16][tag16|bf16]) via relaxed sc1 stores; consumers sweep-poll
// the data words directly. No flags, no counter chain, no fences, no drains.
// 2 barriers/step. Act tile double-buffered in LDS, staged reg->LDS (T14).

#define NWG     64
#define LSTEPS  512
#define BATCH   64
#define HDIM    512
#define ADIM    256
#define GDIM    2048
#define LROW    1024              // Albuf row stride: 512 h + 2x256 act slots
#define LBH     (LSTEPS*BATCH*HDIM)
#define HTW     (BATCH*HDIM)      // tagged u32 words per buffer (32768)

typedef __attribute__((ext_vector_type(4))) float f32x4;
typedef __attribute__((ext_vector_type(8))) short s16x8;
typedef unsigned long long u64t;

__device__ __forceinline__ unsigned short f2bf(float f){
  unsigned u = __builtin_bit_cast(unsigned, f);
  u = (u + 0x7fffu + ((u >> 16) & 1u)) >> 16;   // round-to-nearest-even
  return (unsigned short)u;
}
__device__ __forceinline__ float sigm(float x){ return 1.f / (1.f + __expf(-x)); }
__device__ __forceinline__ float ftanh(float x){ return 1.f - 2.f / (__expf(2.f*x) + 1.f); }

// ---------------- precompute kernels ----------------

__global__ void cvt_act(const float* __restrict__ in, unsigned short* __restrict__ ob, int n8){
  int i = blockIdx.x * blockDim.x + threadIdx.x;
  if (i >= n8) return;
  const float4* p = (const float4*)in + (size_t)i * 2;
  float4 a = p[0], b = p[1];
  int4 o;
  o.x = (int)((unsigned)f2bf(a.x) | ((unsigned)f2bf(a.y) << 16));
  o.y = (int)((unsigned)f2bf(a.z) | ((unsigned)f2bf(a.w) << 16));
  o.z = (int)((unsigned)f2bf(b.x) | ((unsigned)f2bf(b.y) << 16));
  o.w = (int)((unsigned)f2bf(b.z) | ((unsigned)f2bf(b.w) << 16));
  ((int4*)ob)[i] = o;
}

__global__ void static_gates_k(const float* __restrict__ inp, const float* __restrict__ Wih,
                               const float* __restrict__ bih, const float* __restrict__ bhh,
                               float* __restrict__ statg){
  int g = blockIdx.x;
  int b = threadIdx.x;
  const float4* w = (const float4*)(Wih + (size_t)g * 512);
  const float4* x = (const float4*)(inp + (size_t)b * 256);
  float acc = 0.f;
#pragma unroll 8
  for (int i = 0; i < 64; ++i){
    float4 wv = w[i], xv = x[i];
    acc += wv.x*xv.x + wv.y*xv.y + wv.z*xv.z + wv.w*xv.w;
  }
  statg[b*GDIM + g] = acc + bih[g] + bhh[g];
}

// buffer 0 <- h0 with tag 0 (one u32 word per element)
__global__ void init_h(const float* __restrict__ h0, unsigned int* __restrict__ hbuf){
  int i = blockIdx.x * blockDim.x + threadIdx.x;
  if (i < HTW) hbuf[i] = (unsigned)f2bf(h0[i]);   // tag 0 in high 16
}

// ---------------- persistent LSTM kernel ----------------

__global__ __launch_bounds__(256, 1) void lstm_persistent(
    const unsigned short* __restrict__ act_bf,   // [L][B][A] bf16
    const float*          __restrict__ statg,    // [B][4H]
    const float*          __restrict__ Whh,      // [4H][H]
    const float*          __restrict__ Wih,      // [4H][I+A]
    const float*          __restrict__ c0,       // [B][H]
    float*                __restrict__ out,      // hs, h_n, c_n
    unsigned int*         __restrict__ hbuf)     // [2][HTW] tagged h words
{
  __shared__ short Albuf[64 * LROW];   // [batch 64][512 h | 256 act0 | 256 act1]
  __shared__ float gbuf[64 * 36];      // gate staging, padded stride 36

  const int tid  = threadIdx.x;
  const int wgk  = blockIdx.x;         // owns hidden units [8*wgk, 8*wgk+8)
  const int lane = tid & 63;
  const int wid  = tid >> 6;
  const int wm   = wid & 1;
  const int wn   = wid >> 1;
  const int kgrp = (lane >> 4) * 8;

  // ---- B fragments (weights) in registers (R2 layout) ----
  const int cl   = wn*16 + (lane & 15);                // local col 0..31
  const int grow = (cl >> 3)*512 + wgk*8 + (cl & 7);   // global gate row
  s16x8 bw[24];
#pragma unroll
  for (int kk = 0; kk < 16; ++kk){                     // K 0..511 : W_hh
    s16x8 v;
    const int kb = kk*32 + kgrp;
#pragma unroll
    for (int e = 0; e < 8; ++e)
      v[e] = (short)f2bf(Whh[(size_t)grow*512 + kb + e]);
    bw[kk] = v;
  }
#pragma unroll
  for (int kk = 16; kk < 24; ++kk){                    // K 512..767 : W_a
    s16x8 v;
    const int kb = kk*32 + kgrp;
#pragma unroll
    for (int e = 0; e < 8; ++e)
      v[e] = (short)f2bf(Wih[(size_t)grow*512 + (kb - 256) + e]);
    bw[kk] = v;
  }

  // ---- cell-update mapping: thread -> (batch b_cu, units j0, j0+1) ----
  const int b_cu = tid >> 2;           // 0..63
  const int u0   = (tid & 3) * 2;      // 0,2,4,6
  const int j0   = wgk*8 + u0;
  float stat2[2][4], cr[2];
#pragma unroll
  for (int pi = 0; pi < 2; ++pi){
    const int j = j0 + pi;
#pragma unroll
    for (int g4 = 0; g4 < 4; ++g4)
      stat2[pi][g4] = statg[b_cu*GDIM + g4*512 + j];
    cr[pi] = c0[b_cu*HDIM + j];
  }

  // ---- prologue: stage act(0) into slot 0 ----
  {
    const unsigned short* asrc = act_bf;
#pragma unroll
    for (int it = 0; it < 8; ++it){
      const int idx = it*256 + tid;
      const int r = idx >> 5, ch = idx & 31;
      int4 v = *(const int4*)(asrc + r*ADIM + ch*8);
      *(int4*)(&Albuf[r*LROW + 512 + ((ch ^ (r & 7)) * 8)]) = v;
    }
  }

  for (int t = 0; t < LSTEPS; ++t){
    const int aslot = t & 1;

    // ---- 1. tagged sweep-poll + stage h (single visibility hop) ----
    {
      const u64t* hsrc = (const u64t*)(hbuf + (size_t)(t & 1) * HTW);
      const unsigned tagv = (unsigned)t;
      unsigned okm;
      do {
        okm = 1u;
#pragma unroll
        for (int it = 0; it < 16; ++it){
          const int idx = it*256 + tid;
          const int r = idx >> 6, ch = idx & 63;
          const u64t* p = hsrc + (r*256 + ch*4);
          u64t w0 = __hip_atomic_load(p+0, __ATOMIC_RELAXED, __HIP_MEMORY_SCOPE_AGENT);
          u64t w1 = __hip_atomic_load(p+1, __ATOMIC_RELAXED, __HIP_MEMORY_SCOPE_AGENT);
          u64t w2 = __hip_atomic_load(p+2, __ATOMIC_RELAXED, __HIP_MEMORY_SCOPE_AGENT);
          u64t w3 = __hip_atomic_load(p+3, __ATOMIC_RELAXED, __HIP_MEMORY_SCOPE_AGENT);
          okm &= (unsigned)(
              ((((unsigned)(w0 >> 16)) & 0xffffu) == tagv) & (((unsigned)(w0 >> 48)) == tagv)
            & ((((unsigned)(w1 >> 16)) & 0xffffu) == tagv) & (((unsigned)(w1 >> 48)) == tagv)
            & ((((unsigned)(w2 >> 16)) & 0xffffu) == tagv) & (((unsigned)(w2 >> 48)) == tagv)
            & ((((unsigned)(w3 >> 16)) & 0xffffu) == tagv) & (((unsigned)(w3 >> 48)) == tagv));
          int4 v;
          v.x = (int)(((unsigned)w0 & 0xffffu) | ((((unsigned)(w0 >> 32)) & 0xffffu) << 16));
          v.y = (int)(((unsigned)w1 & 0xffffu) | ((((unsigned)(w1 >> 32)) & 0xffffu) << 16));
          v.z = (int)(((unsigned)w2 & 0xffffu) | ((((unsigned)(w2 >> 32)) & 0xffffu) << 16));
          v.w = (int)(((unsigned)w3 & 0xffffu) | ((((unsigned)(w3 >> 32)) & 0xffffu) << 16));
          *(int4*)(&Albuf[r*LROW + ((ch ^ (r & 7)) * 8)]) = v;
        }
      } while (__builtin_expect(okm == 0u, 0));
    }
    __syncthreads();   // B1: h staged (and act slot writes of t-1 ordered)

    // ---- 2. prestage act(t+1): HBM -> regs (issue only; hides under MFMA) ----
    int4 pre[8];
    if (t < LSTEPS-1){
      const unsigned short* asrc = act_bf + (size_t)(t+1) * (BATCH*ADIM);
#pragma unroll
      for (int it = 0; it < 8; ++it){
        const int idx = it*256 + tid;
        const int r = idx >> 5, ch = idx & 31;
        pre[it] = *(const int4*)(asrc + r*ADIM + ch*8);
      }
    }

    // ---- 3. MFMA: D[64 batch][32 gate cols] over K=768 ----
    f32x4 acc[2];
#pragma unroll
    for (int m = 0; m < 2; ++m){
      f32x4 a = {0.f, 0.f, 0.f, 0.f};
      const int r  = wm*32 + m*16 + (lane & 15);
      const short* arow = &Albuf[r * LROW];
      const int sw = (r & 7) * 8;
#pragma unroll
      for (int kk = 0; kk < 16; ++kk){                 // h part
        const int col = (kk*32 + kgrp) ^ sw;
        s16x8 af = *(const s16x8*)(arow + col);
        a = __builtin_amdgcn_mfma_f32_16x16x32_bf16(af, bw[kk], a, 0, 0, 0);
      }
      const short* aact = arow + 512 + aslot*256;
#pragma unroll
      for (int kk = 16; kk < 24; ++kk){                // act part (slot t&1)
        const int col = (((kk-16)*32 + kgrp)) ^ sw;
        s16x8 af = *(const s16x8*)(aact + col);
        a = __builtin_amdgcn_mfma_f32_16x16x32_bf16(af, bw[kk], a, 0, 0, 0);
      }
      acc[m] = a;
    }
    // scatter gates to LDS (C/D layout: col=lane&15, row=(lane>>4)*4+reg)
#pragma unroll
    for (int m = 0; m < 2; ++m){
      const int base_b = wm*32 + m*16 + ((lane >> 4) * 4);
#pragma unroll
      for (int r4 = 0; r4 < 4; ++r4)
        gbuf[(base_b + r4)*36 + cl] = acc[m][r4];
    }
    __syncthreads();   // B2: gbuf complete; also fences MFMA reads vs next sweep

    // ---- 4. elementwise LSTM cell ----
    float hv[2];
    {
      const float* gb = &gbuf[b_cu*36];
#pragma unroll
      for (int pi = 0; pi < 2; ++pi){
        const int u = u0 + pi;
        float iv = gb[u]      + stat2[pi][0];
        float fv = gb[8 + u]  + stat2[pi][1];
        float gv = gb[16 + u] + stat2[pi][2];
        float ov = gb[24 + u] + stat2[pi][3];
        iv = sigm(iv); fv = sigm(fv); gv = ftanh(gv); ov = sigm(ov);
        float c = fv * cr[pi] + iv * gv;
        cr[pi] = c;
        hv[pi] = ov * ftanh(c);
      }
    }

    // ---- 5. publish tagged h (one u64 sc1 store; no drain, no flag) ----
    if (t < LSTEPS-1){
      const unsigned tagw = (unsigned)(t+1);
      u64t lo = (u64t)((tagw << 16) | (unsigned)f2bf(hv[0]));
      u64t hi = (u64t)((tagw << 16) | (unsigned)f2bf(hv[1]));
      u64t val = lo | (hi << 32);
      u64t* dst = (u64t*)(hbuf + (size_t)((t+1) & 1) * HTW) + (b_cu*256 + (j0 >> 1));
      __hip_atomic_store(dst, val, __ATOMIC_RELAXED, __HIP_MEMORY_SCOPE_AGENT);
    }

    // ---- 6. act(t+1) regs -> LDS slot (t+1)&1 ----
    if (t < LSTEPS-1){
#pragma unroll
      for (int it = 0; it < 8; ++it){
        const int idx = it*256 + tid;
        const int r = idx >> 5, ch = idx & 31;
        *(int4*)(&Albuf[r*LROW + 512 + ((t+1) & 1)*256 + ((ch ^ (r & 7)) * 8)]) = pre[it];
      }
    }

    // ---- 7. hs output (+ finals) ----
    {
      float2 h2o; h2o.x = hv[0]; h2o.y = hv[1];
      *(float2*)&out[((size_t)t*BATCH + b_cu)*HDIM + j0] = h2o;
      if (t == LSTEPS-1){
        float2 c2o; c2o.x = cr[0]; c2o.y = cr[1];
        *(float2*)&out[LBH + b_cu*HDIM + j0] = h2o;
        *(float2*)&out[LBH + BATCH*HDIM + b_cu*HDIM + j0] = c2o;
      }
    }
  }
}

// ---------------- launch ----------------

extern "C" void kernel_launch(void* const* d_in, const int* in_sizes, int n_in,
                              void* d_out, int out_size, void* d_ws, size_t ws_size,
                              hipStream_t stream){
  const float* act = (const float*)d_in[0];
  const float* inp = (const float*)d_in[1];
  const float* h0  = (const float*)d_in[2];
  const float* c0  = (const float*)d_in[3];
  const float* Wih = (const float*)d_in[4];
  const float* Whh = (const float*)d_in[5];
  const float* bih = (const float*)d_in[6];
  const float* bhh = (const float*)d_in[7];
  float* out = (float*)d_out;

  char* ws = (char*)d_ws;
  unsigned short* act_bf = (unsigned short*)ws;                      // 16 MiB
  unsigned int*   hbuf   = (unsigned int*)(ws + 16777216);           // 256 KiB tagged
  float*          statg  = (float*)(ws + 16777216 + 262144);         // 512 KiB

  // erase stale tags from previous replays (ABA safety), then init h0 (tag 0)
  hipMemsetAsync(hbuf, 0xFF, 2 * HTW * sizeof(unsigned int), stream);
  cvt_act<<<4096, 256, 0, stream>>>(act, act_bf, (LSTEPS*BATCH*ADIM)/8);
  static_gates_k<<<GDIM, 64, 0, stream>>>(inp, Wih, bih, bhh, statg);
  init_h<<<128, 256, 0, stream>>>(h0, hbuf);
  lstm_persistent<<<NWG, 256, 0, stream>>>(act_bf, statg, Whh, Wih, c0, out, hbuf);
}

// Round 8
// 3521.329 us; speedup vs baseline: 1.6303x; 1.6303x over previous
//
#include <hip/hip_runtime.h>
#include <hip/hip_bf16.h>

// LSTM decoder: L=512, B=64, A=256, I=256, H=512, 4H=2048.
// R8: per-XCD replicated recurrence. 256 WGs (1/CU, LDS-forced) -> exactly
// 32 WGs per XCD. Each WG reads physical XCC_ID and joins its XCD's replica
// (roles claimed via per-XCD counter). Each replica runs the full LSTM
// independently; h exchanged through the XCD's own L2 (plain stores +
// sc0 loads). No agent atomics / fences in the loop. hs output striped
// across replicas by t&7.

#define NWG     256
#define THREADS 256
#define LSTEPS  512
#define BATCH   64
#define HDIM    512
#define ADIM    256
#define GDIM    2048
#define KTOT    768
#define LBH     (LSTEPS*BATCH*HDIM)
#define HWORDS  (BATCH*256)      // u32 words per h buffer (16384 = 64 KiB)
#define NXCD    8
#define RPX     32               // roles (WGs) per XCD

typedef __attribute__((ext_vector_type(4))) float f32x4;
typedef __attribute__((ext_vector_type(8))) short s16x8;
typedef unsigned long long u64t;

__device__ __forceinline__ unsigned f2bf(float f){
  unsigned u = __builtin_bit_cast(unsigned, f);
  u = (u + 0x7fffu + ((u >> 16) & 1u)) >> 16;   // round-to-nearest-even
  return u;
}
__device__ __forceinline__ float sigm(float x){ return 1.f / (1.f + __expf(-x)); }
__device__ __forceinline__ float ftanh(float x){ return 1.f - 2.f / (__expf(2.f*x) + 1.f); }

// ---------------- precompute kernels ----------------

__global__ void cvt_act(const float* __restrict__ in, unsigned short* __restrict__ ob, int n8){
  int i = blockIdx.x * blockDim.x + threadIdx.x;
  if (i >= n8) return;
  const float4* p = (const float4*)in + (size_t)i * 2;
  float4 a = p[0], b = p[1];
  int4 o;
  o.x = (int)(f2bf(a.x) | (f2bf(a.y) << 16));
  o.y = (int)(f2bf(a.z) | (f2bf(a.w) << 16));
  o.z = (int)(f2bf(b.x) | (f2bf(b.y) << 16));
  o.w = (int)(f2bf(b.z) | (f2bf(b.w) << 16));
  ((int4*)ob)[i] = o;
}

__global__ void static_gates_k(const float* __restrict__ inp, const float* __restrict__ Wih,
                               const float* __restrict__ bih, const float* __restrict__ bhh,
                               float* __restrict__ statg){
  int g = blockIdx.x;
  int b = threadIdx.x;
  const float4* w = (const float4*)(Wih + (size_t)g * 512);
  const float4* x = (const float4*)(inp + (size_t)b * 256);
  float acc = 0.f;
#pragma unroll 8
  for (int i = 0; i < 64; ++i){
    float4 wv = w[i], xv = x[i];
    acc += wv.x*xv.x + wv.y*xv.y + wv.z*xv.z + wv.w*xv.w;
  }
  statg[b*GDIM + g] = acc + bih[g] + bhh[g];
}

// ---------------- persistent LSTM kernel (per-XCD replicas) ----------------

__global__ __launch_bounds__(256, 1) void lstm_persistent(
    const unsigned short* __restrict__ act_bf,   // [L][B][A] bf16
    const float*          __restrict__ statg,    // [B][4H]
    const float*          __restrict__ Whh,      // [4H][H]
    const float*          __restrict__ Wih,      // [4H][I+A]
    const float*          __restrict__ h0g,      // [B][H] fp32
    const float*          __restrict__ c0,       // [B][H]
    float*                __restrict__ out,      // hs, h_n, c_n
    unsigned int*         __restrict__ hbuf,     // [8 xcd][2][HWORDS]
    unsigned int*         __restrict__ done,     // [8 xcd][8 slot][32 role]
    unsigned int*         __restrict__ rctr)     // [8] role counters
{
  __shared__ short Albuf[64 * KTOT];   // [batch 64][512 h | 256 act] bf16, swizzled
  __shared__ float gbuf[64 * 68];      // [batch 64][64 gate cols], pad 4
  __shared__ int   role_sh;

  const int tid  = threadIdx.x;
  const int lane = tid & 63;
  const int wid  = tid >> 6;           // wave 0..3

  unsigned xcd;
  asm("s_getreg_b32 %0, hwreg(HW_REG_XCC_ID)" : "=s"(xcd));
  xcd &= 7;

  if (tid == 0)
    role_sh = (int)__hip_atomic_fetch_add(&rctr[xcd], 1u, __ATOMIC_RELAXED,
                                          __HIP_MEMORY_SCOPE_AGENT);
  __syncthreads();
  const int role = role_sh;
  if (role >= RPX) return;             // paranoia guard (argued impossible)

  unsigned int* hrep = hbuf + (size_t)xcd * 2 * HWORDS;
  unsigned int* drep = done + (size_t)xcd * 8 * RPX;

  // ---- B fragments (weights) in registers ----
  // wave wid handles gate g4=wid for all 16 owned units: col cl = wid*16+(lane&15)
  const int cl   = wid*16 + (lane & 15);
  const int grow = (cl >> 4)*512 + role*16 + (cl & 15);  // global gate row
  const int kgrp = (lane >> 4) * 8;
  s16x8 bw[24];
#pragma unroll
  for (int kk = 0; kk < 16; ++kk){                       // K 0..511 : W_hh
    s16x8 v;
    const int kb = kk*32 + kgrp;
#pragma unroll
    for (int e = 0; e < 8; ++e)
      v[e] = (short)f2bf(Whh[(size_t)grow*512 + kb + e]);
    bw[kk] = v;
  }
#pragma unroll
  for (int kk = 16; kk < 24; ++kk){                      // K 512..767 : W_a
    s16x8 v;
    const int kb = kk*32 + kgrp;
#pragma unroll
    for (int e = 0; e < 8; ++e)
      v[e] = (short)f2bf(Wih[(size_t)grow*512 + (kb - 256) + e]);
    bw[kk] = v;
  }

  // ---- cell mapping: thread -> (batch b_cu, units u0..u0+3) ----
  const int b_cu = tid >> 2;           // 0..63
  const int u0   = (tid & 3) * 4;      // 0,4,8,12
  float stat4[4][4], cr[4];
#pragma unroll
  for (int ui = 0; ui < 4; ++ui){
    const int j = role*16 + u0 + ui;
#pragma unroll
    for (int g4 = 0; g4 < 4; ++g4)
      stat4[ui][g4] = statg[b_cu*GDIM + g4*512 + j];
    cr[ui] = c0[b_cu*HDIM + j];
  }

  // ---- prologue: stage act(0) ----
  {
    const unsigned short* asrc = act_bf;
#pragma unroll
    for (int it = 0; it < 8; ++it){
      const int idx = it*THREADS + tid;
      const int r = idx >> 5, ch = idx & 31;
      int4 v = *(const int4*)(asrc + r*ADIM + ch*8);
      *(int4*)(&Albuf[r*KTOT + 512 + ((ch ^ (r & 7)) * 8)]) = v;
    }
  }

  for (int t = 0; t < LSTEPS; ++t){
    // ---- wait for h(t) flags (wave 0 only), then join ----
    if (t > 0){
      if (wid == 0){
        const unsigned* fl = drep + (t & 7)*RPX + (lane & 31);
        unsigned v; int guard = 0;
        do {
          asm volatile("global_load_dword %0, %1, off sc0\n\ts_waitcnt vmcnt(0)"
                       : "=v"(v) : "v"(fl) : "memory");
        } while (!__all(v == (unsigned)t) && ++guard < 200000);
      }
      __syncthreads();   // Bp: flags confirmed
      // ---- stage h(t) from XCD-local L2 (sc0 loads, batch of 16) ----
      const unsigned int* hsrc = hrep + (size_t)(t & 1) * HWORDS;
      int4 hv16[16];
#pragma unroll
      for (int it = 0; it < 16; ++it){
        const int idx = it*THREADS + tid;
        const int r = idx >> 6, ch = idx & 63;
        const unsigned int* p = hsrc + r*256 + ch*4;
        asm volatile("global_load_dwordx4 %0, %1, off sc0" : "=v"(hv16[it]) : "v"(p));
      }
      asm volatile("s_waitcnt vmcnt(0)" ::: "memory");
#pragma unroll
      for (int it = 0; it < 16; ++it){
        const int idx = it*THREADS + tid;
        const int r = idx >> 6, ch = idx & 63;
        *(int4*)(&Albuf[r*KTOT + ((ch ^ (r & 7)) * 8)]) = hv16[it];
      }
    } else {
      // t==0: stage bf16(h0) from global fp32
#pragma unroll
      for (int it = 0; it < 16; ++it){
        const int idx = it*THREADS + tid;
        const int r = idx >> 6, ch = idx & 63;
        const float* hp = h0g + r*HDIM + ch*8;
        float4 a = *(const float4*)hp, b = *(const float4*)(hp + 4);
        int4 v;
        v.x = (int)(f2bf(a.x) | (f2bf(a.y) << 16));
        v.y = (int)(f2bf(a.z) | (f2bf(a.w) << 16));
        v.z = (int)(f2bf(b.x) | (f2bf(b.y) << 16));
        v.w = (int)(f2bf(b.z) | (f2bf(b.w) << 16));
        *(int4*)(&Albuf[r*KTOT + ((ch ^ (r & 7)) * 8)]) = v;
      }
    }
    __syncthreads();   // B1: tile staged

    // ---- MFMA: D[64 batch][64 gate cols] over K=768; wave = 4 m-tiles ----
    f32x4 acc[4];
#pragma unroll
    for (int m = 0; m < 4; ++m){
      f32x4 a = {0.f, 0.f, 0.f, 0.f};
      const int r  = m*16 + (lane & 15);
      const short* arow = &Albuf[r * KTOT];
      const int sw = (r & 7) * 8;
#pragma unroll
      for (int kk = 0; kk < 24; ++kk){
        const int col = (kk*32 + kgrp) ^ sw;
        s16x8 af = *(const s16x8*)(arow + col);
        a = __builtin_amdgcn_mfma_f32_16x16x32_bf16(af, bw[kk], a, 0, 0, 0);
      }
      acc[m] = a;
    }
#pragma unroll
    for (int m = 0; m < 4; ++m){
      const int base_b = m*16 + ((lane >> 4) * 4);
#pragma unroll
      for (int r4 = 0; r4 < 4; ++r4)
        gbuf[(base_b + r4)*68 + cl] = acc[m][r4];
    }
    __syncthreads();   // B2: gbuf complete

    // ---- cell update (4 units) + publish h(t+1) into XCD-local L2 ----
    float hv[4];
    {
      const float* gb = &gbuf[b_cu*68];
#pragma unroll
      for (int ui = 0; ui < 4; ++ui){
        const int u = u0 + ui;
        float iv = sigm (gb[u]      + stat4[ui][0]);
        float fv = sigm (gb[16 + u] + stat4[ui][1]);
        float gv = ftanh(gb[32 + u] + stat4[ui][2]);
        float ov = sigm (gb[48 + u] + stat4[ui][3]);
        float c = fv * cr[ui] + iv * gv;
        cr[ui] = c;
        hv[ui] = ov * ftanh(c);
      }
    }
    if (t < LSTEPS-1){
      unsigned w0 = f2bf(hv[0]) | (f2bf(hv[1]) << 16);
      unsigned w1 = f2bf(hv[2]) | (f2bf(hv[3]) << 16);
      u64t val = (u64t)w0 | ((u64t)w1 << 32);
      *(u64t*)(hrep + (size_t)((t+1) & 1)*HWORDS + b_cu*256 + role*8 + (u0 >> 1)) = val;
    }
    __syncthreads();   // B3: vmcnt(0) drain -> publishes in L2
    if (t < LSTEPS-1 && tid == 0){
      unsigned* fd = drep + ((t+1) & 7)*RPX + role;
      unsigned tv = (unsigned)(t+1);
      asm volatile("global_store_dword %0, %1, off" :: "v"(fd), "v"(tv) : "memory");
    }

    // ---- off critical path: striped hs output, finals, act prestage ----
    if ((int)xcd == (t & 7)){
      float4 ho; ho.x = hv[0]; ho.y = hv[1]; ho.z = hv[2]; ho.w = hv[3];
      *(float4*)&out[((size_t)t*BATCH + b_cu)*HDIM + role*16 + u0] = ho;
      if (t == LSTEPS-1){
        float4 co; co.x = cr[0]; co.y = cr[1]; co.z = cr[2]; co.w = cr[3];
        *(float4*)&out[LBH + b_cu*HDIM + role*16 + u0] = ho;
        *(float4*)&out[LBH + BATCH*HDIM + b_cu*HDIM + role*16 + u0] = co;
      }
    }
    if (t < LSTEPS-1){
      const unsigned short* asrc = act_bf + (size_t)(t+1) * (BATCH*ADIM);
#pragma unroll
      for (int it = 0; it < 8; ++it){
        const int idx = it*THREADS + tid;
        const int r = idx >> 5, ch = idx & 31;
        int4 v = *(const int4*)(asrc + r*ADIM + ch*8);
        *(int4*)(&Albuf[r*KTOT + 512 + ((ch ^ (r & 7)) * 8)]) = v;
      }
    }
  }

  // ---- clear own flag slots (cross-replay hygiene) ----
  if (tid == 0){
#pragma unroll
    for (int s = 0; s < 8; ++s){
      unsigned* fd = drep + s*RPX + role;
      unsigned z = 0u;
      asm volatile("global_store_dword %0, %1, off" :: "v"(fd), "v"(z) : "memory");
    }
  }
}

// ---------------- launch ----------------

extern "C" void kernel_launch(void* const* d_in, const int* in_sizes, int n_in,
                              void* d_out, int out_size, void* d_ws, size_t ws_size,
                              hipStream_t stream){
  const float* act = (const float*)d_in[0];
  const float* inp = (const float*)d_in[1];
  const float* h0  = (const float*)d_in[2];
  const float* c0  = (const float*)d_in[3];
  const float* Wih = (const float*)d_in[4];
  const float* Whh = (const float*)d_in[5];
  const float* bih = (const float*)d_in[6];
  const float* bhh = (const float*)d_in[7];
  float* out = (float*)d_out;

  char* ws = (char*)d_ws;
  unsigned short* act_bf = (unsigned short*)ws;                            // 16 MiB
  unsigned int*   hbuf   = (unsigned int*)(ws + 16777216);                 // 1 MiB
  float*          statg  = (float*)(ws + 16777216 + 1048576);              // 512 KiB
  unsigned int*   done   = (unsigned int*)(ws + 16777216 + 1048576 + 524288); // 8 KiB
  unsigned int*   rctr   = (unsigned int*)(ws + 16777216 + 1048576 + 524288 + 8192);

  hipMemsetAsync(done, 0, NXCD*8*RPX*sizeof(unsigned int), stream);
  hipMemsetAsync(rctr, 0, NXCD*sizeof(unsigned int), stream);
  cvt_act<<<4096, 256, 0, stream>>>(act, act_bf, (LSTEPS*BATCH*ADIM)/8);
  static_gates_k<<<GDIM, 64, 0, stream>>>(inp, Wih, bih, bhh, statg);
  lstm_persistent<<<NWG, THREADS, 0, stream>>>(act_bf, statg, Whh, Wih, h0, c0,
                                               out, hbuf, done, rctr);
}